// Round 17
// baseline (294.279 us; speedup 1.0000x reference)
//
#include <hip/hip_runtime.h>
#include <math.h>

#define SLOPE 0.01f
#define FC1_BLOCKS 512
#define NB 128         // CSR buckets (R17: 64->128 for k_sortb CU coverage)
#define HBLK 256       // histogram blocks in k_front
#define BCHUNK 2048    // edges per k_bucket block

// ---------------------------------------------------------------------------
// R1: scatter->CSR gather. R2: fc1a 512 blocks. R3: f32+float4. R4: bucketed
// CSR fill. R5: multi-block scan; hws=hw*dinv. R6: split head. R7: bucket
// histogram counts. R8: 4x4 register tiles. R9 REGRESSED (slicing killed
// coalescing; line granularity matters). R10: 8-edge unroll. R11-12: bf16
// hws. R13: bf16 acts + u16 srcs. R14: k_fused gather+next-matmul. R15: wide
// h0 stores, k_tail. R16: in-bucket counting sort, zero global atomics in
// CSR chain (288us).
// R17: NB 64->128 (k_sortb was 64 blocks on 256 CUs); 16-edge unroll in the
//      fattest gather (k_fused<64>). Remaining time is random-line gather
//      traffic near the L2/L3 random-access ceiling.
// ---------------------------------------------------------------------------

static inline int cdiv_l(long a, int b) { return (int)((a + (long)b - 1) / (long)b); }

__device__ __forceinline__ unsigned short f2bf(float f) {   // RNE
    union { float f; unsigned int i; } x; x.f = f;
    unsigned int i = x.i;
    i += 0x7fffu + ((i >> 16) & 1u);
    return (unsigned short)(i >> 16);
}
__device__ __forceinline__ float bf2f(unsigned short u) {
    union { unsigned int i; float f; } x; x.i = ((unsigned int)u) << 16;
    return x.f;
}
__device__ __forceinline__ float4 bf2f4(ushort4 u) {
    return make_float4(bf2f(u.x), bf2f(u.y), bf2f(u.z), bf2f(u.w));
}
__device__ __forceinline__ ushort4 f2bf4(float4 f) {
    return make_ushort4(f2bf(f.x), f2bf(f.y), f2bf(f.z), f2bf(f.w));
}

// ---- merged front: bucket histogram (bhist) | h0 bf16 | W1 pad ----------
__global__ void k_front(const int* __restrict__ col, int* __restrict__ bhist, int E, int S,
                        const float* __restrict__ x, const float* __restrict__ emb,
                        unsigned short* __restrict__ h0, int N,
                        const float* __restrict__ W1, float* __restrict__ W1p,
                        int h0Blocks) {
    int b = blockIdx.x;
    if (b < HBLK) {
        __shared__ int hist[NB];
        int t = threadIdx.x;
        if (t < NB) hist[t] = 0;
        __syncthreads();
        for (int e = b * 256 + t; e < E; e += HBLK * 256)
            atomicAdd(&hist[col[e] / S], 1);
        __syncthreads();
        if (t < NB) bhist[b * NB + t] = hist[t];
        return;
    }
    b -= HBLK;
    if (b < h0Blocks) {
        int idx = b * 256 + threadIdx.x;      // one thread per 4 h0 elements
        if (idx >= N * 32) return;
        int i = idx >> 5;
        int g = idx & 31;                      // k = 4g .. 4g+3
        const float* xr = x + (long)i * 5;
        int id0 = (int)xr[0], id1 = (int)xr[1];
        const float* e0p = emb + (long)id0 * 62;
        const float* e1p = emb + (long)id1 * 62;
        float v[4];
#pragma unroll
        for (int kk = 0; kk < 4; ++kk) {
            int k = 4 * g + kk;
            float val;
            if (k < 62)       val = e0p[k];
            else if (k < 124) val = e1p[k - 62];
            else if (k < 127) val = xr[2 + (k - 124)];
            else              val = 0.f;
            v[kk] = val;
        }
        *(ushort4*)(h0 + (long)i * 128 + 4 * g) =
            make_ushort4(f2bf(v[0]), f2bf(v[1]), f2bf(v[2]), f2bf(v[3]));
        return;
    }
    b -= h0Blocks;
    {   // W1 pad: 128x64, row 127 = 0
        int idx = b * 256 + threadIdx.x;
        if (idx >= 128 * 64) return;
        int k = idx >> 6;
        W1p[idx] = (k < 127) ? W1[idx] : 0.f;
    }
}

// column-sum bhist (2 parts x 128 cols) -> exclusive scan -> gcur + gstart
__global__ void k_bscan(const int* __restrict__ bhist, int* __restrict__ gcur,
                        int* __restrict__ gstart) {
    __shared__ int sums[2][NB];
    __shared__ int sc[NB];
    int t = threadIdx.x;
    int colId = t & 127, part = t >> 7;          // 2 parts x 128 cols
    int s = 0;
    for (int b = part * 128; b < part * 128 + 128; ++b)
        s += bhist[b * NB + colId];
    sums[part][colId] = s;
    __syncthreads();
    if (t < NB) sc[t] = sums[0][t] + sums[1][t];
    __syncthreads();
    int v = (t < NB) ? sc[t] : 0;
    for (int d = 1; d < NB; d <<= 1) {
        int u = (t < NB && t >= d) ? sc[t - d] : 0;
        __syncthreads();
        if (t < NB) sc[t] += u;
        __syncthreads();
    }
    if (t < NB) {
        int excl = sc[t] - v;
        gcur[t] = excl;
        gstart[t] = excl;
        if (t == NB - 1) gstart[NB] = sc[t];   // == E
    }
}

// ---------------- bucket-sort edges ----------------
__global__ void k_bucket(const int* __restrict__ row, const int* __restrict__ col,
                         int* __restrict__ gcur, unsigned int* __restrict__ ebuf,
                         int E, int S) {
    __shared__ int hist[NB], base[NB], lcur[NB];
    int t = threadIdx.x;
    if (t < NB) { hist[t] = 0; lcur[t] = 0; }
    __syncthreads();
    int e0 = blockIdx.x * BCHUNK;
    int e1 = min(e0 + BCHUNK, E);
    for (int e = e0 + t; e < e1; e += blockDim.x)
        atomicAdd(&hist[col[e] / S], 1);
    __syncthreads();
    if (t < NB) base[t] = hist[t] ? atomicAdd(&gcur[t], hist[t]) : 0;
    __syncthreads();
    for (int e = e0 + t; e < e1; e += blockDim.x) {
        int c = col[e], r = row[e];
        int b = c / S;
        int p = base[b] + atomicAdd(&lcur[b], 1);
        ebuf[p] = ((unsigned)c << 16) | (unsigned)r;
    }
}

// ---------------- in-bucket counting sort: off, dinv, srcs in one pass --------------
// one block (512 thr) per bucket; counts/cursors in LDS (S <= 512).
__global__ void k_sortb(const unsigned int* __restrict__ ebuf,
                        const int* __restrict__ gstart,
                        int* __restrict__ off, float* __restrict__ dinv,
                        unsigned short* __restrict__ srcs, int N, int S, int E) {
    __shared__ int cntl[512];
    __shared__ int lcur[512];
    int b = blockIdx.x, t = threadIdx.x;
    int base_node = b * S;
    int nNodes = min(S, N - base_node);
    int start = gstart[b], end = gstart[b + 1];
    if (t < S) cntl[t] = 0;
    __syncthreads();
    for (int e = start + t; e < end; e += blockDim.x)
        atomicAdd(&cntl[(int)(ebuf[e] >> 16) - base_node], 1);
    __syncthreads();
    int myc = (t < S) ? cntl[t] : 0;
    for (int d = 1; d < S; d <<= 1) {
        int u = (t < S && t >= d) ? cntl[t - d] : 0;
        __syncthreads();
        if (t < S) cntl[t] += u;
        __syncthreads();
    }
    if (t < nNodes) {
        int excl = cntl[t] - myc;
        int node = base_node + t;
        off[node] = start + excl;
        dinv[node] = (float)(1.0 / sqrt((double)myc + 1.0));
        lcur[t] = excl;
    }
    if (b == NB - 1 && t == 0) off[N] = E;
    __syncthreads();
    for (int e = start + t; e < end; e += blockDim.x) {
        unsigned p = ebuf[e];
        int cl = (int)(p >> 16) - base_node;
        int pos = start + atomicAdd(&lcur[cl], 1);
        srcs[pos] = (unsigned short)(p & 0xFFFFu);
    }
}

// ---------------- L1 dense: hws = bf16( (h0 @ W1p) * dinv ), 4x4 tiles -------------
template<int DIN, int DOUT>
__global__ void k_hw_rb(const unsigned short* __restrict__ h, int ld,
                        const float* __restrict__ W,
                        const float* __restrict__ dinv, unsigned short* __restrict__ hws,
                        int N) {
    constexpr int Q = DOUT / 4;
    int tid = blockIdx.x * blockDim.x + threadIdx.x;
    int G = (N + 3) >> 2;
    if (tid >= G * Q) return;
    int g = tid / Q;
    int q = tid % Q;
    int i0 = 4 * g;
    const ushort4* h0 = (const ushort4*)(h + (long)i0 * ld);
    const ushort4* h1 = (const ushort4*)(h + (long)(i0 + 1) * ld);
    const ushort4* h2 = (const ushort4*)(h + (long)(i0 + 2) * ld);
    const ushort4* h3 = (const ushort4*)(h + (long)(i0 + 3) * ld);
    const float* wp = W + 4 * q;
    float4 acc0 = make_float4(0.f, 0.f, 0.f, 0.f);
    float4 acc1 = acc0, acc2 = acc0, acc3 = acc0;
#pragma unroll 4
    for (int kk = 0; kk < DIN / 4; ++kk) {
        float4 a0 = bf2f4(h0[kk]), a1 = bf2f4(h1[kk]);
        float4 a2 = bf2f4(h2[kk]), a3 = bf2f4(h3[kk]);
        float4 w0 = *(const float4*)(wp + (long)(4 * kk)     * DOUT);
        float4 w1 = *(const float4*)(wp + (long)(4 * kk + 1) * DOUT);
        float4 w2 = *(const float4*)(wp + (long)(4 * kk + 2) * DOUT);
        float4 w3 = *(const float4*)(wp + (long)(4 * kk + 3) * DOUT);
        acc0.x += a0.x * w0.x + a0.y * w1.x + a0.z * w2.x + a0.w * w3.x;
        acc0.y += a0.x * w0.y + a0.y * w1.y + a0.z * w2.y + a0.w * w3.y;
        acc0.z += a0.x * w0.z + a0.y * w1.z + a0.z * w2.z + a0.w * w3.z;
        acc0.w += a0.x * w0.w + a0.y * w1.w + a0.z * w2.w + a0.w * w3.w;
        acc1.x += a1.x * w0.x + a1.y * w1.x + a1.z * w2.x + a1.w * w3.x;
        acc1.y += a1.x * w0.y + a1.y * w1.y + a1.z * w2.y + a1.w * w3.y;
        acc1.z += a1.x * w0.z + a1.y * w1.z + a1.z * w2.z + a1.w * w3.z;
        acc1.w += a1.x * w0.w + a1.y * w1.w + a1.z * w2.w + a1.w * w3.w;
        acc2.x += a2.x * w0.x + a2.y * w1.x + a2.z * w2.x + a2.w * w3.x;
        acc2.y += a2.x * w0.y + a2.y * w1.y + a2.z * w2.y + a2.w * w3.y;
        acc2.z += a2.x * w0.z + a2.y * w1.z + a2.z * w2.z + a2.w * w3.z;
        acc2.w += a2.x * w0.w + a2.y * w1.w + a2.z * w2.w + a2.w * w3.w;
        acc3.x += a3.x * w0.x + a3.y * w1.x + a3.z * w2.x + a3.w * w3.x;
        acc3.y += a3.x * w0.y + a3.y * w1.y + a3.z * w2.y + a3.w * w3.y;
        acc3.z += a3.x * w0.z + a3.y * w1.z + a3.z * w2.z + a3.w * w3.z;
        acc3.w += a3.x * w0.w + a3.y * w1.w + a3.z * w2.w + a3.w * w3.w;
    }
    float d0 = dinv[i0], d1 = dinv[i0 + 1], d2 = dinv[i0 + 2], d3 = dinv[i0 + 3];
    acc0.x *= d0; acc0.y *= d0; acc0.z *= d0; acc0.w *= d0;
    acc1.x *= d1; acc1.y *= d1; acc1.z *= d1; acc1.w *= d1;
    acc2.x *= d2; acc2.y *= d2; acc2.z *= d2; acc2.w *= d2;
    acc3.x *= d3; acc3.y *= d3; acc3.z *= d3; acc3.w *= d3;
    unsigned short* op = hws + (long)i0 * DOUT + 4 * q;
    *(ushort4*)(op) = f2bf4(acc0);
    if (i0 + 1 < N) *(ushort4*)(op + DOUT)     = f2bf4(acc1);
    if (i0 + 2 < N) *(ushort4*)(op + 2 * DOUT) = f2bf4(acc2);
    if (i0 + 3 < N) *(ushort4*)(op + 3 * DOUT) = f2bf4(acc3);
}

// ---------------- fused: gather layer l (DG-dim) -> act -> matmul W (DG x 32) -------
template<int DG, int UNROLL16>
__global__ void k_fused(const int* __restrict__ off,
                        const unsigned short* __restrict__ srcs,
                        const float* __restrict__ dinv,
                        const unsigned short* __restrict__ hin,
                        const float* __restrict__ bg, int mode,
                        const float* __restrict__ W,
                        unsigned short* __restrict__ hwsOut, int N) {
    constexpr int QG = DG / 4;
    constexpr int NPB = 256 / QG;
    __shared__ float hrow[NPB][DG + 4];
    int t = threadIdx.x;
    int n = t / QG, q = t % QG;
    int c = blockIdx.x * NPB + n;
    if (c < N) {
        int e0 = off[c], e1 = off[c + 1];
        float dc = dinv[c];
        float4 acc = bf2f4(*(const ushort4*)(hin + (long)c * DG + 4 * q));  // self
        int e = e0;
        if (UNROLL16) {
            for (; e + 15 < e1; e += 16) {
                int r[16];
#pragma unroll
                for (int k = 0; k < 16; ++k) r[k] = srcs[e + k];
                ushort4 u[16];
#pragma unroll
                for (int k = 0; k < 16; ++k)
                    u[k] = *(const ushort4*)(hin + (long)r[k] * DG + 4 * q);
#pragma unroll
                for (int k = 0; k < 16; k += 4) {
                    float4 v0 = bf2f4(u[k]),     v1 = bf2f4(u[k + 1]);
                    float4 v2 = bf2f4(u[k + 2]), v3 = bf2f4(u[k + 3]);
                    acc.x += (v0.x + v1.x) + (v2.x + v3.x);
                    acc.y += (v0.y + v1.y) + (v2.y + v3.y);
                    acc.z += (v0.z + v1.z) + (v2.z + v3.z);
                    acc.w += (v0.w + v1.w) + (v2.w + v3.w);
                }
            }
        }
        for (; e + 7 < e1; e += 8) {
            int r0 = srcs[e],     r1 = srcs[e + 1], r2 = srcs[e + 2], r3 = srcs[e + 3];
            int r4 = srcs[e + 4], r5 = srcs[e + 5], r6 = srcs[e + 6], r7 = srcs[e + 7];
            float4 v0 = bf2f4(*(const ushort4*)(hin + (long)r0 * DG + 4 * q));
            float4 v1 = bf2f4(*(const ushort4*)(hin + (long)r1 * DG + 4 * q));
            float4 v2 = bf2f4(*(const ushort4*)(hin + (long)r2 * DG + 4 * q));
            float4 v3 = bf2f4(*(const ushort4*)(hin + (long)r3 * DG + 4 * q));
            float4 v4 = bf2f4(*(const ushort4*)(hin + (long)r4 * DG + 4 * q));
            float4 v5 = bf2f4(*(const ushort4*)(hin + (long)r5 * DG + 4 * q));
            float4 v6 = bf2f4(*(const ushort4*)(hin + (long)r6 * DG + 4 * q));
            float4 v7 = bf2f4(*(const ushort4*)(hin + (long)r7 * DG + 4 * q));
            acc.x += (v0.x + v1.x) + (v2.x + v3.x);
            acc.y += (v0.y + v1.y) + (v2.y + v3.y);
            acc.z += (v0.z + v1.z) + (v2.z + v3.z);
            acc.w += (v0.w + v1.w) + (v2.w + v3.w);
            acc.x += (v4.x + v5.x) + (v6.x + v7.x);
            acc.y += (v4.y + v5.y) + (v6.y + v7.y);
            acc.z += (v4.z + v5.z) + (v6.z + v7.z);
            acc.w += (v4.w + v5.w) + (v6.w + v7.w);
        }
        for (; e + 3 < e1; e += 4) {
            int r0 = srcs[e], r1 = srcs[e + 1], r2 = srcs[e + 2], r3 = srcs[e + 3];
            float4 v0 = bf2f4(*(const ushort4*)(hin + (long)r0 * DG + 4 * q));
            float4 v1 = bf2f4(*(const ushort4*)(hin + (long)r1 * DG + 4 * q));
            float4 v2 = bf2f4(*(const ushort4*)(hin + (long)r2 * DG + 4 * q));
            float4 v3 = bf2f4(*(const ushort4*)(hin + (long)r3 * DG + 4 * q));
            acc.x += (v0.x + v1.x) + (v2.x + v3.x);
            acc.y += (v0.y + v1.y) + (v2.y + v3.y);
            acc.z += (v0.z + v1.z) + (v2.z + v3.z);
            acc.w += (v0.w + v1.w) + (v2.w + v3.w);
        }
        for (; e < e1; ++e) {
            int r = srcs[e];
            float4 v = bf2f4(*(const ushort4*)(hin + (long)r * DG + 4 * q));
            acc.x += v.x; acc.y += v.y; acc.z += v.z; acc.w += v.w;
        }
        float4 bb = *(const float4*)(bg + 4 * q);
        float t0 = acc.x * dc + bb.x, t1 = acc.y * dc + bb.y;
        float t2 = acc.z * dc + bb.z, t3 = acc.w * dc + bb.w;
        float4 res;
        if (mode == 0) {
            res.x = (t0 >= 0.f) ? t0 : SLOPE * t0;
            res.y = (t1 >= 0.f) ? t1 : SLOPE * t1;
            res.z = (t2 >= 0.f) ? t2 : SLOPE * t2;
            res.w = (t3 >= 0.f) ? t3 : SLOPE * t3;
        } else {
            res.x = (t0 >= 0.f) ? 2.f * t0 : (1.f + SLOPE) * t0;
            res.y = (t1 >= 0.f) ? 2.f * t1 : (1.f + SLOPE) * t1;
            res.z = (t2 >= 0.f) ? 2.f * t2 : (1.f + SLOPE) * t2;
            res.w = (t3 >= 0.f) ? 2.f * t3 : (1.f + SLOPE) * t3;
        }
        *(float4*)&hrow[n][4 * q] = res;
    }
    __syncthreads();
    // phase 2: per-node matmul (DG x 32), 8 threads/node, 4 outputs each
    int n2 = t >> 3;
    int q2 = t & 7;
    if (n2 < NPB) {
        int c2 = blockIdx.x * NPB + n2;
        if (c2 < N) {
            const float* wp = W + 4 * q2;
            float4 acc = make_float4(0.f, 0.f, 0.f, 0.f);
#pragma unroll
            for (int kk = 0; kk < DG / 4; ++kk) {
                float4 a = *(const float4*)&hrow[n2][4 * kk];
                float4 w0 = *(const float4*)(wp + (long)(4 * kk)     * 32);
                float4 w1 = *(const float4*)(wp + (long)(4 * kk + 1) * 32);
                float4 w2 = *(const float4*)(wp + (long)(4 * kk + 2) * 32);
                float4 w3 = *(const float4*)(wp + (long)(4 * kk + 3) * 32);
                acc.x += a.x * w0.x + a.y * w1.x + a.z * w2.x + a.w * w3.x;
                acc.y += a.x * w0.y + a.y * w1.y + a.z * w2.y + a.w * w3.y;
                acc.z += a.x * w0.z + a.y * w1.z + a.z * w2.z + a.w * w3.z;
                acc.w += a.x * w0.w + a.y * w1.w + a.z * w2.w + a.w * w3.w;
            }
            float di = dinv[c2];
            acc.x *= di; acc.y *= di; acc.z *= di; acc.w *= di;
            *(ushort4*)(hwsOut + (long)c2 * 32 + 4 * q2) = f2bf4(acc);
        }
    }
}

// fused last: gather (32-dim, mode1) -> act -> dot W5 (32x1) -> f32 hws
__global__ void k_fused_last(const int* __restrict__ off,
                             const unsigned short* __restrict__ srcs,
                             const float* __restrict__ dinv,
                             const unsigned short* __restrict__ hin,
                             const float* __restrict__ bg,
                             const float* __restrict__ W5,
                             float* __restrict__ hwsOut, int N) {
    constexpr int QG = 8;
    constexpr int NPB = 32;
    __shared__ float hrow[NPB][36];
    int t = threadIdx.x;
    int n = t / QG, q = t % QG;
    int c = blockIdx.x * NPB + n;
    if (c < N) {
        int e0 = off[c], e1 = off[c + 1];
        float dc = dinv[c];
        float4 acc = bf2f4(*(const ushort4*)(hin + (long)c * 32 + 4 * q));
        int e = e0;
        for (; e + 7 < e1; e += 8) {
            int r0 = srcs[e],     r1 = srcs[e + 1], r2 = srcs[e + 2], r3 = srcs[e + 3];
            int r4 = srcs[e + 4], r5 = srcs[e + 5], r6 = srcs[e + 6], r7 = srcs[e + 7];
            float4 v0 = bf2f4(*(const ushort4*)(hin + (long)r0 * 32 + 4 * q));
            float4 v1 = bf2f4(*(const ushort4*)(hin + (long)r1 * 32 + 4 * q));
            float4 v2 = bf2f4(*(const ushort4*)(hin + (long)r2 * 32 + 4 * q));
            float4 v3 = bf2f4(*(const ushort4*)(hin + (long)r3 * 32 + 4 * q));
            float4 v4 = bf2f4(*(const ushort4*)(hin + (long)r4 * 32 + 4 * q));
            float4 v5 = bf2f4(*(const ushort4*)(hin + (long)r5 * 32 + 4 * q));
            float4 v6 = bf2f4(*(const ushort4*)(hin + (long)r6 * 32 + 4 * q));
            float4 v7 = bf2f4(*(const ushort4*)(hin + (long)r7 * 32 + 4 * q));
            acc.x += (v0.x + v1.x) + (v2.x + v3.x);
            acc.y += (v0.y + v1.y) + (v2.y + v3.y);
            acc.z += (v0.z + v1.z) + (v2.z + v3.z);
            acc.w += (v0.w + v1.w) + (v2.w + v3.w);
            acc.x += (v4.x + v5.x) + (v6.x + v7.x);
            acc.y += (v4.y + v5.y) + (v6.y + v7.y);
            acc.z += (v4.z + v5.z) + (v6.z + v7.z);
            acc.w += (v4.w + v5.w) + (v6.w + v7.w);
        }
        for (; e + 3 < e1; e += 4) {
            int r0 = srcs[e], r1 = srcs[e + 1], r2 = srcs[e + 2], r3 = srcs[e + 3];
            float4 v0 = bf2f4(*(const ushort4*)(hin + (long)r0 * 32 + 4 * q));
            float4 v1 = bf2f4(*(const ushort4*)(hin + (long)r1 * 32 + 4 * q));
            float4 v2 = bf2f4(*(const ushort4*)(hin + (long)r2 * 32 + 4 * q));
            float4 v3 = bf2f4(*(const ushort4*)(hin + (long)r3 * 32 + 4 * q));
            acc.x += (v0.x + v1.x) + (v2.x + v3.x);
            acc.y += (v0.y + v1.y) + (v2.y + v3.y);
            acc.z += (v0.z + v1.z) + (v2.z + v3.z);
            acc.w += (v0.w + v1.w) + (v2.w + v3.w);
        }
        for (; e < e1; ++e) {
            int r = srcs[e];
            float4 v = bf2f4(*(const ushort4*)(hin + (long)r * 32 + 4 * q));
            acc.x += v.x; acc.y += v.y; acc.z += v.z; acc.w += v.w;
        }
        float4 bb = *(const float4*)(bg + 4 * q);
        float t0 = acc.x * dc + bb.x, t1 = acc.y * dc + bb.y;
        float t2 = acc.z * dc + bb.z, t3 = acc.w * dc + bb.w;
        float4 res;   // mode 1
        res.x = (t0 >= 0.f) ? 2.f * t0 : (1.f + SLOPE) * t0;
        res.y = (t1 >= 0.f) ? 2.f * t1 : (1.f + SLOPE) * t1;
        res.z = (t2 >= 0.f) ? 2.f * t2 : (1.f + SLOPE) * t2;
        res.w = (t3 >= 0.f) ? 2.f * t3 : (1.f + SLOPE) * t3;
        *(float4*)&hrow[n][4 * q] = res;
    }
    __syncthreads();
    if (t < NPB) {
        int c2 = blockIdx.x * NPB + t;
        if (c2 < N) {
            float acc = 0.f;
#pragma unroll
            for (int kk = 0; kk < 8; ++kk) {
                float4 a = *(const float4*)&hrow[t][4 * kk];
                acc += a.x * W5[4 * kk] + a.y * W5[4 * kk + 1]
                     + a.z * W5[4 * kk + 2] + a.w * W5[4 * kk + 3];
            }
            hwsOut[c2] = acc * dinv[c2];
        }
    }
}

// ---------------- tail: final gather (V in LDS) + fc1a partials fused ---------------
__global__ void k_tail(const int* __restrict__ off,
                       const unsigned short* __restrict__ srcs,
                       const float* __restrict__ dinv, const float* __restrict__ hws,
                       const float* __restrict__ b5,
                       const float* __restrict__ Wf1, double* __restrict__ part,
                       int N, int chunk) {
    __shared__ float Vl[96];
    int bl = blockIdx.x, t = threadIdx.x;
    int i0 = bl * chunk;
    int i1 = min(i0 + chunk, N);
    int cnt = i1 - i0;
    if (t < cnt) {
        int c = i0 + t;
        int e0 = off[c], e1 = off[c + 1];
        float acc = hws[c];
        float a1 = 0.f, a2 = 0.f, a3 = 0.f;
        int e = e0;
        for (; e + 3 < e1; e += 4) {
            acc += hws[srcs[e]];
            a1  += hws[srcs[e + 1]];
            a2  += hws[srcs[e + 2]];
            a3  += hws[srcs[e + 3]];
        }
        for (; e < e1; ++e) acc += hws[srcs[e]];
        float tt = (acc + a1 + a2 + a3) * dinv[c] + b5[0];
        Vl[t] = (tt >= 0.f) ? tt : SLOPE * tt;
    }
    __syncthreads();
    int j = t;   // 128 threads, one per output column
    double a0 = 0.0, a1 = 0.0, a2 = 0.0, a3 = 0.0;
    int i = 0;
    for (; i + 3 < cnt; i += 4) {
        a0 += (double)Vl[i]     * (double)Wf1[(long)(i0 + i)     * 128 + j];
        a1 += (double)Vl[i + 1] * (double)Wf1[(long)(i0 + i + 1) * 128 + j];
        a2 += (double)Vl[i + 2] * (double)Wf1[(long)(i0 + i + 2) * 128 + j];
        a3 += (double)Vl[i + 3] * (double)Wf1[(long)(i0 + i + 3) * 128 + j];
    }
    for (; i < cnt; ++i)
        a0 += (double)Vl[i] * (double)Wf1[(long)(i0 + i) * 128 + j];
    part[bl * 128 + j] = (a0 + a1) + (a2 + a3);
}

__global__ void k_fc1b(const double* __restrict__ part, const float* __restrict__ bf1,
                       float* __restrict__ o1) {
    __shared__ double red[256];
    int j = blockIdx.x;
    int t = threadIdx.x;
    double a = part[t * 128 + j] + part[(t + 256) * 128 + j];
    red[t] = a;
    __syncthreads();
    for (int s = 128; s > 0; s >>= 1) {
        if (t < s) red[t] += red[t + s];
        __syncthreads();
    }
    if (t == 0) {
        double v = red[0] + (double)bf1[j];
        o1[j] = (float)((v > 0.0) ? v : 0.0);
    }
}

__global__ void k_fc2(const float* __restrict__ o1, const float* __restrict__ Wf2,
                      const float* __restrict__ bf2, float* __restrict__ out) {
    __shared__ double red[128];
    int j = blockIdx.x;
    int k = threadIdx.x;
    red[k] = (double)o1[k] * (double)Wf2[(long)k * 128 + j];
    __syncthreads();
    for (int s = 64; s > 0; s >>= 1) {
        if (k < s) red[k] += red[k + s];
        __syncthreads();
    }
    if (k == 0) {
        double u = red[0] + (double)bf2[j];
        out[j] = (float)((u > 0.0) ? u : 0.0);
    }
}

extern "C" void kernel_launch(void* const* d_in, const int* in_sizes, int n_in,
                              void* d_out, int out_size, void* d_ws, size_t ws_size,
                              hipStream_t stream) {
    const float* x   = (const float*)d_in[0];
    const int*   ei  = (const int*)d_in[1];
    const float* emb = (const float*)d_in[2];
    const float* W1  = (const float*)d_in[3];
    const float* b1  = (const float*)d_in[4];
    const float* W2  = (const float*)d_in[5];
    const float* b2  = (const float*)d_in[6];
    const float* W3  = (const float*)d_in[7];
    const float* b3  = (const float*)d_in[8];
    const float* W4  = (const float*)d_in[9];
    const float* b4  = (const float*)d_in[10];
    const float* W5  = (const float*)d_in[11];
    const float* b5  = (const float*)d_in[12];
    const float* Wf1 = (const float*)d_in[13];
    const float* bf1 = (const float*)d_in[14];
    const float* Wf2 = (const float*)d_in[15];
    const float* bf2 = (const float*)d_in[16];

    const int N = in_sizes[0] / 5;
    const int E = in_sizes[1] / 2;
    const int* row = ei;
    const int* col = ei + E;
    const int S = (N + NB - 1) / NB;           // bucket width (~300, <= 512)
    const int Np = N + 4;                       // padded rows for 4-node tiles

    // --- workspace carving ---
    char* ws = (char*)d_ws;
    size_t off_b = 0;
    auto alloc = [&](size_t bytes) -> void* {
        void* p = ws + off_b;
        off_b += (bytes + 255) & ~(size_t)255;
        return p;
    };
    int*   offcsr = (int*)alloc((size_t)(N + 1) * sizeof(int));
    int*   bhist  = (int*)alloc((size_t)HBLK * NB * sizeof(int));
    int*   gcur   = (int*)alloc((size_t)NB * sizeof(int));
    int*   gstart = (int*)alloc((size_t)(NB + 1) * sizeof(int));
    unsigned short* srcs = (unsigned short*)alloc((size_t)E * sizeof(unsigned short));
    unsigned int* ebuf = (unsigned int*)alloc((size_t)E * sizeof(unsigned int));
    float* dinv   = (float*)alloc((size_t)Np * sizeof(float));
    float* W1p    = (float*)alloc((size_t)128 * 64 * sizeof(float));
    unsigned short* H0   = (unsigned short*)alloc((size_t)Np * 128 * sizeof(unsigned short));
    unsigned short* X64  = (unsigned short*)alloc((size_t)Np * 64 * sizeof(unsigned short));
    unsigned short* X32a = (unsigned short*)alloc((size_t)Np * 32 * sizeof(unsigned short));
    unsigned short* X32b = (unsigned short*)alloc((size_t)Np * 32 * sizeof(unsigned short));
    unsigned short* X32c = (unsigned short*)alloc((size_t)Np * 32 * sizeof(unsigned short));
    float* HWSf   = (float*)alloc((size_t)Np * sizeof(float));
    double* part  = (double*)alloc((size_t)FC1_BLOCKS * 128 * sizeof(double));
    float* O1     = (float*)alloc(128 * sizeof(float));

    // --- front: merged (bucket-hist -> bhist | h0 bf16 x4 | W1pad) ---
    int h0Blocks  = cdiv_l((long)N * 32, 256);
    int padBlocks = cdiv_l(128 * 64, 256);
    k_front<<<HBLK + h0Blocks + padBlocks, 256, 0, stream>>>(
        col, bhist, E, S, x, emb, H0, N, W1, W1p, h0Blocks);

    // --- CSR build: bscan -> bucket -> in-bucket counting sort ---
    k_bscan<<<1, 256, 0, stream>>>(bhist, gcur, gstart);
    k_bucket<<<cdiv_l(E, BCHUNK), 256, 0, stream>>>(row, col, gcur, ebuf, E, S);
    k_sortb<<<NB, 512, 0, stream>>>(ebuf, gstart, offcsr, dinv, srcs, N, S, E);

    // --- GCN: L1 dense, then fused gather+matmul chain ---
    {
        int G = (N + 3) / 4;
        k_hw_rb<128, 64><<<cdiv_l((long)G * 16, 256), 256, 0, stream>>>(
            H0, 128, W1p, dinv, X64, N);
    }
    k_fused<64, 1><<<cdiv_l(N, 16), 256, 0, stream>>>(
        offcsr, srcs, dinv, X64, b1, 0, W2, X32a, N);
    k_fused<32, 0><<<cdiv_l(N, 32), 256, 0, stream>>>(
        offcsr, srcs, dinv, X32a, b2, 0, W3, X32b, N);
    k_fused<32, 0><<<cdiv_l(N, 32), 256, 0, stream>>>(
        offcsr, srcs, dinv, X32b, b3, 1, W4, X32c, N);
    k_fused_last<<<cdiv_l(N, 32), 256, 0, stream>>>(
        offcsr, srcs, dinv, X32c, b4, W5, HWSf, N);

    // --- tail: final gather + fc1a fused; then fc1b, fc2 ---
    int chunk = (N + FC1_BLOCKS - 1) / FC1_BLOCKS;   // 75 (< 96 LDS cap)
    k_tail<<<FC1_BLOCKS, 128, 0, stream>>>(
        offcsr, srcs, dinv, HWSf, b5, Wf1, part, N, chunk);
    k_fc1b<<<128, 256, 0, stream>>>(part, bf1, O1);
    k_fc2<<<128, 128, 0, stream>>>(O1, Wf2, bf2, (float*)d_out);
}

// Round 18
// 287.273 us; speedup vs baseline: 1.0244x; 1.0244x over previous
//
#include <hip/hip_runtime.h>
#include <math.h>

#define SLOPE 0.01f
#define FC1_BLOCKS 512
#define NB 64          // CSR buckets
#define HBLK 256       // histogram blocks in k_front
#define BCHUNK 2048    // edges per k_bucket block

// ---------------------------------------------------------------------------
// R1: scatter->CSR gather. R2: fc1a 512 blocks. R3: f32+float4. R4: bucketed
// CSR fill. R5: multi-block scan; hws=hw*dinv. R6: split head. R7: bucket
// histogram counts. R8: 4x4 register tiles. R9 REGRESSED (slicing killed
// coalescing). R10: 8-edge unroll. R11-12: bf16 hws. R13: bf16 acts + u16
// srcs. R14: k_fused gather+next-matmul. R15: wide h0 stores, k_tail.
// R16: in-bucket counting sort, zero global atomics in CSR chain (288us).
// R17 REGRESSED (294us): NB 128 + 16-edge unroll -- register pressure in
//     k_fused<64> (r[16]+u[16] live) and finer bucket histograms hurt.
// R18: exact revert to R16 (best known, 288us). Remaining time is random-
//     line gather traffic near the L2/L3 random-access ceiling; storage is
//     16-bit, fusion/launch-count exhausted. This is the practical plateau.
// ---------------------------------------------------------------------------

static inline int cdiv_l(long a, int b) { return (int)((a + (long)b - 1) / (long)b); }

__device__ __forceinline__ unsigned short f2bf(float f) {   // RNE
    union { float f; unsigned int i; } x; x.f = f;
    unsigned int i = x.i;
    i += 0x7fffu + ((i >> 16) & 1u);
    return (unsigned short)(i >> 16);
}
__device__ __forceinline__ float bf2f(unsigned short u) {
    union { unsigned int i; float f; } x; x.i = ((unsigned int)u) << 16;
    return x.f;
}
__device__ __forceinline__ float4 bf2f4(ushort4 u) {
    return make_float4(bf2f(u.x), bf2f(u.y), bf2f(u.z), bf2f(u.w));
}
__device__ __forceinline__ ushort4 f2bf4(float4 f) {
    return make_ushort4(f2bf(f.x), f2bf(f.y), f2bf(f.z), f2bf(f.w));
}

// ---- merged front: bucket histogram (bhist) | h0 bf16 | W1 pad ----------
__global__ void k_front(const int* __restrict__ col, int* __restrict__ bhist, int E, int S,
                        const float* __restrict__ x, const float* __restrict__ emb,
                        unsigned short* __restrict__ h0, int N,
                        const float* __restrict__ W1, float* __restrict__ W1p,
                        int h0Blocks) {
    int b = blockIdx.x;
    if (b < HBLK) {
        __shared__ int hist[NB];
        int t = threadIdx.x;
        if (t < NB) hist[t] = 0;
        __syncthreads();
        for (int e = b * 256 + t; e < E; e += HBLK * 256)
            atomicAdd(&hist[col[e] / S], 1);
        __syncthreads();
        if (t < NB) bhist[b * NB + t] = hist[t];
        return;
    }
    b -= HBLK;
    if (b < h0Blocks) {
        int idx = b * 256 + threadIdx.x;      // one thread per 4 h0 elements
        if (idx >= N * 32) return;
        int i = idx >> 5;
        int g = idx & 31;                      // k = 4g .. 4g+3
        const float* xr = x + (long)i * 5;
        int id0 = (int)xr[0], id1 = (int)xr[1];
        const float* e0p = emb + (long)id0 * 62;
        const float* e1p = emb + (long)id1 * 62;
        float v[4];
#pragma unroll
        for (int kk = 0; kk < 4; ++kk) {
            int k = 4 * g + kk;
            float val;
            if (k < 62)       val = e0p[k];
            else if (k < 124) val = e1p[k - 62];
            else if (k < 127) val = xr[2 + (k - 124)];
            else              val = 0.f;
            v[kk] = val;
        }
        *(ushort4*)(h0 + (long)i * 128 + 4 * g) =
            make_ushort4(f2bf(v[0]), f2bf(v[1]), f2bf(v[2]), f2bf(v[3]));
        return;
    }
    b -= h0Blocks;
    {   // W1 pad: 128x64, row 127 = 0
        int idx = b * 256 + threadIdx.x;
        if (idx >= 128 * 64) return;
        int k = idx >> 6;
        W1p[idx] = (k < 127) ? W1[idx] : 0.f;
    }
}

// column-sum bhist (parallel) -> exclusive scan -> gcur (cursors) + gstart (fixed)
__global__ void k_bscan(const int* __restrict__ bhist, int* __restrict__ gcur,
                        int* __restrict__ gstart) {
    __shared__ int sums[4][NB];
    __shared__ int sc[NB];
    int t = threadIdx.x;
    int colId = t & 63, part = t >> 6;
    int s = 0;
    for (int b = part * 64; b < part * 64 + 64; ++b)
        s += bhist[b * NB + colId];
    sums[part][colId] = s;
    __syncthreads();
    if (t < NB) {
        int v = sums[0][t] + sums[1][t] + sums[2][t] + sums[3][t];
        sc[t] = v;
    }
    __syncthreads();
    int v = (t < NB) ? sc[t] : 0;
    for (int d = 1; d < NB; d <<= 1) {
        int u = (t < NB && t >= d) ? sc[t - d] : 0;
        __syncthreads();
        if (t < NB) sc[t] += u;
        __syncthreads();
    }
    if (t < NB) {
        int excl = sc[t] - v;
        gcur[t] = excl;
        gstart[t] = excl;
        if (t == NB - 1) gstart[NB] = sc[t];   // == E
    }
}

// ---------------- bucket-sort edges ----------------
__global__ void k_bucket(const int* __restrict__ row, const int* __restrict__ col,
                         int* __restrict__ gcur, unsigned int* __restrict__ ebuf,
                         int E, int S) {
    __shared__ int hist[NB], base[NB], lcur[NB];
    int t = threadIdx.x;
    if (t < NB) { hist[t] = 0; lcur[t] = 0; }
    __syncthreads();
    int e0 = blockIdx.x * BCHUNK;
    int e1 = min(e0 + BCHUNK, E);
    for (int e = e0 + t; e < e1; e += blockDim.x)
        atomicAdd(&hist[col[e] / S], 1);
    __syncthreads();
    if (t < NB) base[t] = hist[t] ? atomicAdd(&gcur[t], hist[t]) : 0;
    __syncthreads();
    for (int e = e0 + t; e < e1; e += blockDim.x) {
        int c = col[e], r = row[e];
        int b = c / S;
        int p = base[b] + atomicAdd(&lcur[b], 1);
        ebuf[p] = ((unsigned)c << 16) | (unsigned)r;
    }
}

// ---------------- in-bucket counting sort: off, dinv, srcs in one pass --------------
// one block per bucket; all counts/cursors in LDS (S <= 1024).
__global__ void k_sortb(const unsigned int* __restrict__ ebuf,
                        const int* __restrict__ gstart,
                        int* __restrict__ off, float* __restrict__ dinv,
                        unsigned short* __restrict__ srcs, int N, int S, int E) {
    __shared__ int cntl[1024];
    __shared__ int lcur[1024];
    int b = blockIdx.x, t = threadIdx.x;
    int base_node = b * S;
    int nNodes = min(S, N - base_node);
    int start = gstart[b], end = gstart[b + 1];
    if (t < S) cntl[t] = 0;
    __syncthreads();
    for (int e = start + t; e < end; e += blockDim.x)
        atomicAdd(&cntl[(int)(ebuf[e] >> 16) - base_node], 1);
    __syncthreads();
    int myc = (t < S) ? cntl[t] : 0;
    // inclusive Hillis-Steele scan over S entries
    for (int d = 1; d < S; d <<= 1) {
        int u = (t < S && t >= d) ? cntl[t - d] : 0;
        __syncthreads();
        if (t < S) cntl[t] += u;
        __syncthreads();
    }
    if (t < nNodes) {
        int excl = cntl[t] - myc;
        int node = base_node + t;
        off[node] = start + excl;
        dinv[node] = (float)(1.0 / sqrt((double)myc + 1.0));
        lcur[t] = excl;
    }
    if (b == NB - 1 && t == 0) off[N] = E;
    __syncthreads();
    for (int e = start + t; e < end; e += blockDim.x) {
        unsigned p = ebuf[e];
        int cl = (int)(p >> 16) - base_node;
        int pos = start + atomicAdd(&lcur[cl], 1);
        srcs[pos] = (unsigned short)(p & 0xFFFFu);
    }
}

// ---------------- L1 dense: hws = bf16( (h0 @ W1p) * dinv ), 4x4 tiles -------------
template<int DIN, int DOUT>
__global__ void k_hw_rb(const unsigned short* __restrict__ h, int ld,
                        const float* __restrict__ W,
                        const float* __restrict__ dinv, unsigned short* __restrict__ hws,
                        int N) {
    constexpr int Q = DOUT / 4;
    int tid = blockIdx.x * blockDim.x + threadIdx.x;
    int G = (N + 3) >> 2;
    if (tid >= G * Q) return;
    int g = tid / Q;
    int q = tid % Q;
    int i0 = 4 * g;
    const ushort4* h0 = (const ushort4*)(h + (long)i0 * ld);
    const ushort4* h1 = (const ushort4*)(h + (long)(i0 + 1) * ld);
    const ushort4* h2 = (const ushort4*)(h + (long)(i0 + 2) * ld);
    const ushort4* h3 = (const ushort4*)(h + (long)(i0 + 3) * ld);
    const float* wp = W + 4 * q;
    float4 acc0 = make_float4(0.f, 0.f, 0.f, 0.f);
    float4 acc1 = acc0, acc2 = acc0, acc3 = acc0;
#pragma unroll 4
    for (int kk = 0; kk < DIN / 4; ++kk) {
        float4 a0 = bf2f4(h0[kk]), a1 = bf2f4(h1[kk]);
        float4 a2 = bf2f4(h2[kk]), a3 = bf2f4(h3[kk]);
        float4 w0 = *(const float4*)(wp + (long)(4 * kk)     * DOUT);
        float4 w1 = *(const float4*)(wp + (long)(4 * kk + 1) * DOUT);
        float4 w2 = *(const float4*)(wp + (long)(4 * kk + 2) * DOUT);
        float4 w3 = *(const float4*)(wp + (long)(4 * kk + 3) * DOUT);
        acc0.x += a0.x * w0.x + a0.y * w1.x + a0.z * w2.x + a0.w * w3.x;
        acc0.y += a0.x * w0.y + a0.y * w1.y + a0.z * w2.y + a0.w * w3.y;
        acc0.z += a0.x * w0.z + a0.y * w1.z + a0.z * w2.z + a0.w * w3.z;
        acc0.w += a0.x * w0.w + a0.y * w1.w + a0.z * w2.w + a0.w * w3.w;
        acc1.x += a1.x * w0.x + a1.y * w1.x + a1.z * w2.x + a1.w * w3.x;
        acc1.y += a1.x * w0.y + a1.y * w1.y + a1.z * w2.y + a1.w * w3.y;
        acc1.z += a1.x * w0.z + a1.y * w1.z + a1.z * w2.z + a1.w * w3.z;
        acc1.w += a1.x * w0.w + a1.y * w1.w + a1.z * w2.w + a1.w * w3.w;
        acc2.x += a2.x * w0.x + a2.y * w1.x + a2.z * w2.x + a2.w * w3.x;
        acc2.y += a2.x * w0.y + a2.y * w1.y + a2.z * w2.y + a2.w * w3.y;
        acc2.z += a2.x * w0.z + a2.y * w1.z + a2.z * w2.z + a2.w * w3.z;
        acc2.w += a2.x * w0.w + a2.y * w1.w + a2.z * w2.w + a2.w * w3.w;
        acc3.x += a3.x * w0.x + a3.y * w1.x + a3.z * w2.x + a3.w * w3.x;
        acc3.y += a3.x * w0.y + a3.y * w1.y + a3.z * w2.y + a3.w * w3.y;
        acc3.z += a3.x * w0.z + a3.y * w1.z + a3.z * w2.z + a3.w * w3.z;
        acc3.w += a3.x * w0.w + a3.y * w1.w + a3.z * w2.w + a3.w * w3.w;
    }
    float d0 = dinv[i0], d1 = dinv[i0 + 1], d2 = dinv[i0 + 2], d3 = dinv[i0 + 3];
    acc0.x *= d0; acc0.y *= d0; acc0.z *= d0; acc0.w *= d0;
    acc1.x *= d1; acc1.y *= d1; acc1.z *= d1; acc1.w *= d1;
    acc2.x *= d2; acc2.y *= d2; acc2.z *= d2; acc2.w *= d2;
    acc3.x *= d3; acc3.y *= d3; acc3.z *= d3; acc3.w *= d3;
    unsigned short* op = hws + (long)i0 * DOUT + 4 * q;
    *(ushort4*)(op) = f2bf4(acc0);
    if (i0 + 1 < N) *(ushort4*)(op + DOUT)     = f2bf4(acc1);
    if (i0 + 2 < N) *(ushort4*)(op + 2 * DOUT) = f2bf4(acc2);
    if (i0 + 3 < N) *(ushort4*)(op + 3 * DOUT) = f2bf4(acc3);
}

// ---------------- fused: gather layer l (DG-dim) -> act -> matmul W (DG x 32) -------
template<int DG>
__global__ void k_fused(const int* __restrict__ off,
                        const unsigned short* __restrict__ srcs,
                        const float* __restrict__ dinv,
                        const unsigned short* __restrict__ hin,
                        const float* __restrict__ bg, int mode,
                        const float* __restrict__ W,
                        unsigned short* __restrict__ hwsOut, int N) {
    constexpr int QG = DG / 4;
    constexpr int NPB = 256 / QG;
    __shared__ float hrow[NPB][DG + 4];
    int t = threadIdx.x;
    int n = t / QG, q = t % QG;
    int c = blockIdx.x * NPB + n;
    if (c < N) {
        int e0 = off[c], e1 = off[c + 1];
        float dc = dinv[c];
        float4 acc = bf2f4(*(const ushort4*)(hin + (long)c * DG + 4 * q));  // self
        int e = e0;
        for (; e + 7 < e1; e += 8) {
            int r0 = srcs[e],     r1 = srcs[e + 1], r2 = srcs[e + 2], r3 = srcs[e + 3];
            int r4 = srcs[e + 4], r5 = srcs[e + 5], r6 = srcs[e + 6], r7 = srcs[e + 7];
            float4 v0 = bf2f4(*(const ushort4*)(hin + (long)r0 * DG + 4 * q));
            float4 v1 = bf2f4(*(const ushort4*)(hin + (long)r1 * DG + 4 * q));
            float4 v2 = bf2f4(*(const ushort4*)(hin + (long)r2 * DG + 4 * q));
            float4 v3 = bf2f4(*(const ushort4*)(hin + (long)r3 * DG + 4 * q));
            float4 v4 = bf2f4(*(const ushort4*)(hin + (long)r4 * DG + 4 * q));
            float4 v5 = bf2f4(*(const ushort4*)(hin + (long)r5 * DG + 4 * q));
            float4 v6 = bf2f4(*(const ushort4*)(hin + (long)r6 * DG + 4 * q));
            float4 v7 = bf2f4(*(const ushort4*)(hin + (long)r7 * DG + 4 * q));
            acc.x += (v0.x + v1.x) + (v2.x + v3.x);
            acc.y += (v0.y + v1.y) + (v2.y + v3.y);
            acc.z += (v0.z + v1.z) + (v2.z + v3.z);
            acc.w += (v0.w + v1.w) + (v2.w + v3.w);
            acc.x += (v4.x + v5.x) + (v6.x + v7.x);
            acc.y += (v4.y + v5.y) + (v6.y + v7.y);
            acc.z += (v4.z + v5.z) + (v6.z + v7.z);
            acc.w += (v4.w + v5.w) + (v6.w + v7.w);
        }
        for (; e + 3 < e1; e += 4) {
            int r0 = srcs[e], r1 = srcs[e + 1], r2 = srcs[e + 2], r3 = srcs[e + 3];
            float4 v0 = bf2f4(*(const ushort4*)(hin + (long)r0 * DG + 4 * q));
            float4 v1 = bf2f4(*(const ushort4*)(hin + (long)r1 * DG + 4 * q));
            float4 v2 = bf2f4(*(const ushort4*)(hin + (long)r2 * DG + 4 * q));
            float4 v3 = bf2f4(*(const ushort4*)(hin + (long)r3 * DG + 4 * q));
            acc.x += (v0.x + v1.x) + (v2.x + v3.x);
            acc.y += (v0.y + v1.y) + (v2.y + v3.y);
            acc.z += (v0.z + v1.z) + (v2.z + v3.z);
            acc.w += (v0.w + v1.w) + (v2.w + v3.w);
        }
        for (; e < e1; ++e) {
            int r = srcs[e];
            float4 v = bf2f4(*(const ushort4*)(hin + (long)r * DG + 4 * q));
            acc.x += v.x; acc.y += v.y; acc.z += v.z; acc.w += v.w;
        }
        float4 bb = *(const float4*)(bg + 4 * q);
        float t0 = acc.x * dc + bb.x, t1 = acc.y * dc + bb.y;
        float t2 = acc.z * dc + bb.z, t3 = acc.w * dc + bb.w;
        float4 res;
        if (mode == 0) {
            res.x = (t0 >= 0.f) ? t0 : SLOPE * t0;
            res.y = (t1 >= 0.f) ? t1 : SLOPE * t1;
            res.z = (t2 >= 0.f) ? t2 : SLOPE * t2;
            res.w = (t3 >= 0.f) ? t3 : SLOPE * t3;
        } else {
            res.x = (t0 >= 0.f) ? 2.f * t0 : (1.f + SLOPE) * t0;
            res.y = (t1 >= 0.f) ? 2.f * t1 : (1.f + SLOPE) * t1;
            res.z = (t2 >= 0.f) ? 2.f * t2 : (1.f + SLOPE) * t2;
            res.w = (t3 >= 0.f) ? 2.f * t3 : (1.f + SLOPE) * t3;
        }
        *(float4*)&hrow[n][4 * q] = res;
    }
    __syncthreads();
    // phase 2: per-node matmul (DG x 32), 8 threads/node, 4 outputs each
    int n2 = t >> 3;
    int q2 = t & 7;
    if (n2 < NPB) {
        int c2 = blockIdx.x * NPB + n2;
        if (c2 < N) {
            const float* wp = W + 4 * q2;
            float4 acc = make_float4(0.f, 0.f, 0.f, 0.f);
#pragma unroll
            for (int kk = 0; kk < DG / 4; ++kk) {
                float4 a = *(const float4*)&hrow[n2][4 * kk];
                float4 w0 = *(const float4*)(wp + (long)(4 * kk)     * 32);
                float4 w1 = *(const float4*)(wp + (long)(4 * kk + 1) * 32);
                float4 w2 = *(const float4*)(wp + (long)(4 * kk + 2) * 32);
                float4 w3 = *(const float4*)(wp + (long)(4 * kk + 3) * 32);
                acc.x += a.x * w0.x + a.y * w1.x + a.z * w2.x + a.w * w3.x;
                acc.y += a.x * w0.y + a.y * w1.y + a.z * w2.y + a.w * w3.y;
                acc.z += a.x * w0.z + a.y * w1.z + a.z * w2.z + a.w * w3.z;
                acc.w += a.x * w0.w + a.y * w1.w + a.z * w2.w + a.w * w3.w;
            }
            float di = dinv[c2];
            acc.x *= di; acc.y *= di; acc.z *= di; acc.w *= di;
            *(ushort4*)(hwsOut + (long)c2 * 32 + 4 * q2) = f2bf4(acc);
        }
    }
}

// fused last: gather (32-dim, mode1) -> act -> dot W5 (32x1) -> f32 hws
__global__ void k_fused_last(const int* __restrict__ off,
                             const unsigned short* __restrict__ srcs,
                             const float* __restrict__ dinv,
                             const unsigned short* __restrict__ hin,
                             const float* __restrict__ bg,
                             const float* __restrict__ W5,
                             float* __restrict__ hwsOut, int N) {
    constexpr int QG = 8;
    constexpr int NPB = 32;
    __shared__ float hrow[NPB][36];
    int t = threadIdx.x;
    int n = t / QG, q = t % QG;
    int c = blockIdx.x * NPB + n;
    if (c < N) {
        int e0 = off[c], e1 = off[c + 1];
        float dc = dinv[c];
        float4 acc = bf2f4(*(const ushort4*)(hin + (long)c * 32 + 4 * q));
        int e = e0;
        for (; e + 7 < e1; e += 8) {
            int r0 = srcs[e],     r1 = srcs[e + 1], r2 = srcs[e + 2], r3 = srcs[e + 3];
            int r4 = srcs[e + 4], r5 = srcs[e + 5], r6 = srcs[e + 6], r7 = srcs[e + 7];
            float4 v0 = bf2f4(*(const ushort4*)(hin + (long)r0 * 32 + 4 * q));
            float4 v1 = bf2f4(*(const ushort4*)(hin + (long)r1 * 32 + 4 * q));
            float4 v2 = bf2f4(*(const ushort4*)(hin + (long)r2 * 32 + 4 * q));
            float4 v3 = bf2f4(*(const ushort4*)(hin + (long)r3 * 32 + 4 * q));
            float4 v4 = bf2f4(*(const ushort4*)(hin + (long)r4 * 32 + 4 * q));
            float4 v5 = bf2f4(*(const ushort4*)(hin + (long)r5 * 32 + 4 * q));
            float4 v6 = bf2f4(*(const ushort4*)(hin + (long)r6 * 32 + 4 * q));
            float4 v7 = bf2f4(*(const ushort4*)(hin + (long)r7 * 32 + 4 * q));
            acc.x += (v0.x + v1.x) + (v2.x + v3.x);
            acc.y += (v0.y + v1.y) + (v2.y + v3.y);
            acc.z += (v0.z + v1.z) + (v2.z + v3.z);
            acc.w += (v0.w + v1.w) + (v2.w + v3.w);
            acc.x += (v4.x + v5.x) + (v6.x + v7.x);
            acc.y += (v4.y + v5.y) + (v6.y + v7.y);
            acc.z += (v4.z + v5.z) + (v6.z + v7.z);
            acc.w += (v4.w + v5.w) + (v6.w + v7.w);
        }
        for (; e + 3 < e1; e += 4) {
            int r0 = srcs[e], r1 = srcs[e + 1], r2 = srcs[e + 2], r3 = srcs[e + 3];
            float4 v0 = bf2f4(*(const ushort4*)(hin + (long)r0 * 32 + 4 * q));
            float4 v1 = bf2f4(*(const ushort4*)(hin + (long)r1 * 32 + 4 * q));
            float4 v2 = bf2f4(*(const ushort4*)(hin + (long)r2 * 32 + 4 * q));
            float4 v3 = bf2f4(*(const ushort4*)(hin + (long)r3 * 32 + 4 * q));
            acc.x += (v0.x + v1.x) + (v2.x + v3.x);
            acc.y += (v0.y + v1.y) + (v2.y + v3.y);
            acc.z += (v0.z + v1.z) + (v2.z + v3.z);
            acc.w += (v0.w + v1.w) + (v2.w + v3.w);
        }
        for (; e < e1; ++e) {
            int r = srcs[e];
            float4 v = bf2f4(*(const ushort4*)(hin + (long)r * 32 + 4 * q));
            acc.x += v.x; acc.y += v.y; acc.z += v.z; acc.w += v.w;
        }
        float4 bb = *(const float4*)(bg + 4 * q);
        float t0 = acc.x * dc + bb.x, t1 = acc.y * dc + bb.y;
        float t2 = acc.z * dc + bb.z, t3 = acc.w * dc + bb.w;
        float4 res;   // mode 1
        res.x = (t0 >= 0.f) ? 2.f * t0 : (1.f + SLOPE) * t0;
        res.y = (t1 >= 0.f) ? 2.f * t1 : (1.f + SLOPE) * t1;
        res.z = (t2 >= 0.f) ? 2.f * t2 : (1.f + SLOPE) * t2;
        res.w = (t3 >= 0.f) ? 2.f * t3 : (1.f + SLOPE) * t3;
        *(float4*)&hrow[n][4 * q] = res;
    }
    __syncthreads();
    if (t < NPB) {
        int c2 = blockIdx.x * NPB + t;
        if (c2 < N) {
            float acc = 0.f;
#pragma unroll
            for (int kk = 0; kk < 8; ++kk) {
                float4 a = *(const float4*)&hrow[t][4 * kk];
                acc += a.x * W5[4 * kk] + a.y * W5[4 * kk + 1]
                     + a.z * W5[4 * kk + 2] + a.w * W5[4 * kk + 3];
            }
            hwsOut[c2] = acc * dinv[c2];
        }
    }
}

// ---------------- tail: final gather (V in LDS) + fc1a partials fused ---------------
__global__ void k_tail(const int* __restrict__ off,
                       const unsigned short* __restrict__ srcs,
                       const float* __restrict__ dinv, const float* __restrict__ hws,
                       const float* __restrict__ b5,
                       const float* __restrict__ Wf1, double* __restrict__ part,
                       int N, int chunk) {
    __shared__ float Vl[96];
    int bl = blockIdx.x, t = threadIdx.x;
    int i0 = bl * chunk;
    int i1 = min(i0 + chunk, N);
    int cnt = i1 - i0;
    if (t < cnt) {
        int c = i0 + t;
        int e0 = off[c], e1 = off[c + 1];
        float acc = hws[c];
        float a1 = 0.f, a2 = 0.f, a3 = 0.f;
        int e = e0;
        for (; e + 3 < e1; e += 4) {
            acc += hws[srcs[e]];
            a1  += hws[srcs[e + 1]];
            a2  += hws[srcs[e + 2]];
            a3  += hws[srcs[e + 3]];
        }
        for (; e < e1; ++e) acc += hws[srcs[e]];
        float tt = (acc + a1 + a2 + a3) * dinv[c] + b5[0];
        Vl[t] = (tt >= 0.f) ? tt : SLOPE * tt;
    }
    __syncthreads();
    int j = t;   // 128 threads, one per output column
    double a0 = 0.0, a1 = 0.0, a2 = 0.0, a3 = 0.0;
    int i = 0;
    for (; i + 3 < cnt; i += 4) {
        a0 += (double)Vl[i]     * (double)Wf1[(long)(i0 + i)     * 128 + j];
        a1 += (double)Vl[i + 1] * (double)Wf1[(long)(i0 + i + 1) * 128 + j];
        a2 += (double)Vl[i + 2] * (double)Wf1[(long)(i0 + i + 2) * 128 + j];
        a3 += (double)Vl[i + 3] * (double)Wf1[(long)(i0 + i + 3) * 128 + j];
    }
    for (; i < cnt; ++i)
        a0 += (double)Vl[i] * (double)Wf1[(long)(i0 + i) * 128 + j];
    part[bl * 128 + j] = (a0 + a1) + (a2 + a3);
}

__global__ void k_fc1b(const double* __restrict__ part, const float* __restrict__ bf1,
                       float* __restrict__ o1) {
    __shared__ double red[256];
    int j = blockIdx.x;
    int t = threadIdx.x;
    double a = part[t * 128 + j] + part[(t + 256) * 128 + j];
    red[t] = a;
    __syncthreads();
    for (int s = 128; s > 0; s >>= 1) {
        if (t < s) red[t] += red[t + s];
        __syncthreads();
    }
    if (t == 0) {
        double v = red[0] + (double)bf1[j];
        o1[j] = (float)((v > 0.0) ? v : 0.0);
    }
}

__global__ void k_fc2(const float* __restrict__ o1, const float* __restrict__ Wf2,
                      const float* __restrict__ bf2, float* __restrict__ out) {
    __shared__ double red[128];
    int j = blockIdx.x;
    int k = threadIdx.x;
    red[k] = (double)o1[k] * (double)Wf2[(long)k * 128 + j];
    __syncthreads();
    for (int s = 64; s > 0; s >>= 1) {
        if (k < s) red[k] += red[k + s];
        __syncthreads();
    }
    if (k == 0) {
        double u = red[0] + (double)bf2[j];
        out[j] = (float)((u > 0.0) ? u : 0.0);
    }
}

extern "C" void kernel_launch(void* const* d_in, const int* in_sizes, int n_in,
                              void* d_out, int out_size, void* d_ws, size_t ws_size,
                              hipStream_t stream) {
    const float* x   = (const float*)d_in[0];
    const int*   ei  = (const int*)d_in[1];
    const float* emb = (const float*)d_in[2];
    const float* W1  = (const float*)d_in[3];
    const float* b1  = (const float*)d_in[4];
    const float* W2  = (const float*)d_in[5];
    const float* b2  = (const float*)d_in[6];
    const float* W3  = (const float*)d_in[7];
    const float* b3  = (const float*)d_in[8];
    const float* W4  = (const float*)d_in[9];
    const float* b4  = (const float*)d_in[10];
    const float* W5  = (const float*)d_in[11];
    const float* b5  = (const float*)d_in[12];
    const float* Wf1 = (const float*)d_in[13];
    const float* bf1 = (const float*)d_in[14];
    const float* Wf2 = (const float*)d_in[15];
    const float* bf2 = (const float*)d_in[16];

    const int N = in_sizes[0] / 5;
    const int E = in_sizes[1] / 2;
    const int* row = ei;
    const int* col = ei + E;
    const int S = (N + NB - 1) / NB;           // bucket width (<= 1024 for N <= 65536)
    const int Np = N + 4;                       // padded rows for 4-node tiles

    // --- workspace carving ---
    char* ws = (char*)d_ws;
    size_t off_b = 0;
    auto alloc = [&](size_t bytes) -> void* {
        void* p = ws + off_b;
        off_b += (bytes + 255) & ~(size_t)255;
        return p;
    };
    int*   offcsr = (int*)alloc((size_t)(N + 1) * sizeof(int));
    int*   bhist  = (int*)alloc((size_t)HBLK * NB * sizeof(int));
    int*   gcur   = (int*)alloc((size_t)NB * sizeof(int));
    int*   gstart = (int*)alloc((size_t)(NB + 1) * sizeof(int));
    unsigned short* srcs = (unsigned short*)alloc((size_t)E * sizeof(unsigned short));
    unsigned int* ebuf = (unsigned int*)alloc((size_t)E * sizeof(unsigned int));
    float* dinv   = (float*)alloc((size_t)Np * sizeof(float));
    float* W1p    = (float*)alloc((size_t)128 * 64 * sizeof(float));
    unsigned short* H0   = (unsigned short*)alloc((size_t)Np * 128 * sizeof(unsigned short));
    unsigned short* X64  = (unsigned short*)alloc((size_t)Np * 64 * sizeof(unsigned short));
    unsigned short* X32a = (unsigned short*)alloc((size_t)Np * 32 * sizeof(unsigned short));
    unsigned short* X32b = (unsigned short*)alloc((size_t)Np * 32 * sizeof(unsigned short));
    unsigned short* X32c = (unsigned short*)alloc((size_t)Np * 32 * sizeof(unsigned short));
    float* HWSf   = (float*)alloc((size_t)Np * sizeof(float));
    double* part  = (double*)alloc((size_t)FC1_BLOCKS * 128 * sizeof(double));
    float* O1     = (float*)alloc(128 * sizeof(float));

    // --- front: merged (bucket-hist -> bhist | h0 bf16 x4 | W1pad) ---
    int h0Blocks  = cdiv_l((long)N * 32, 256);
    int padBlocks = cdiv_l(128 * 64, 256);
    k_front<<<HBLK + h0Blocks + padBlocks, 256, 0, stream>>>(
        col, bhist, E, S, x, emb, H0, N, W1, W1p, h0Blocks);

    // --- CSR build: bscan -> bucket -> in-bucket counting sort ---
    k_bscan<<<1, 256, 0, stream>>>(bhist, gcur, gstart);
    k_bucket<<<cdiv_l(E, BCHUNK), 256, 0, stream>>>(row, col, gcur, ebuf, E, S);
    k_sortb<<<NB, 1024, 0, stream>>>(ebuf, gstart, offcsr, dinv, srcs, N, S, E);

    // --- GCN: L1 dense, then fused gather+matmul chain ---
    {
        int G = (N + 3) / 4;
        k_hw_rb<128, 64><<<cdiv_l((long)G * 16, 256), 256, 0, stream>>>(
            H0, 128, W1p, dinv, X64, N);
    }
    k_fused<64><<<cdiv_l(N, 16), 256, 0, stream>>>(
        offcsr, srcs, dinv, X64, b1, 0, W2, X32a, N);
    k_fused<32><<<cdiv_l(N, 32), 256, 0, stream>>>(
        offcsr, srcs, dinv, X32a, b2, 0, W3, X32b, N);
    k_fused<32><<<cdiv_l(N, 32), 256, 0, stream>>>(
        offcsr, srcs, dinv, X32b, b3, 1, W4, X32c, N);
    k_fused_last<<<cdiv_l(N, 32), 256, 0, stream>>>(
        offcsr, srcs, dinv, X32c, b4, W5, HWSf, N);

    // --- tail: final gather + fc1a fused; then fc1b, fc2 ---
    int chunk = (N + FC1_BLOCKS - 1) / FC1_BLOCKS;   // 75 (< 96 LDS cap)
    k_tail<<<FC1_BLOCKS, 128, 0, stream>>>(
        offcsr, srcs, dinv, HWSf, b5, Wf1, part, N, chunk);
    k_fc1b<<<128, 256, 0, stream>>>(part, bf1, O1);
    k_fc2<<<128, 128, 0, stream>>>(O1, Wf2, bf2, (float*)d_out);
}